// Round 2
// baseline (941.215 us; speedup 1.0000x reference)
//
#include <hip/hip_runtime.h>

// FrozenBNBEmbedding: dequantize-blockwise (int8 codes -> fp32 via 256-entry LUT,
// per-4096-block absmax scale) fused with embedding gather.
// DIM == BLOCK == 4096  =>  one absmax scale per vocab row.
//
// V2.1: wave-per-token persistent decomposition (V2 with nontemporal-store type fix).
//  - 2048 blocks x 256 thr (4 waves) = 8192 waves -> 1 token per wave (grid-stride for generality)
//  - 16 independent int4 loads issued per wave before any dependent use (deep MLP)
//  - token id / absmax forced to scalar path (readfirstlane -> s_load)
//  - non-temporal float4 stores via native ext_vector_type (HIP_vector_type rejected
//    by __builtin_nontemporal_store): output is write-once, keep it out of L2/L3 so
//    weight rows stay cache-resident across iterations

#define DIM 4096

typedef float  fx4 __attribute__((ext_vector_type(4)));

__global__ __launch_bounds__(256) void bnb_embed_kernel(
    const int* __restrict__ tokens,    // [n_tokens] token ids
    const int* __restrict__ weight,    // [VOCAB, DIM] int8 codes stored as int32
    const float* __restrict__ absmax,  // [VOCAB] per-row scale (n_blocks == VOCAB here)
    const float* __restrict__ code,    // [256] LUT
    float* __restrict__ out,           // [n_tokens, DIM] fp32
    int n_tokens)
{
    __shared__ float lut[256];
    lut[threadIdx.x] = code[threadIdx.x];
    __syncthreads();

    const int wave = threadIdx.x >> 6;   // 0..3
    const int lane = threadIdx.x & 63;
    const int waveGlobal  = blockIdx.x * 4 + wave;
    const int nWavesTotal = gridDim.x * 4;

    for (int tok = waveGlobal; tok < n_tokens; tok += nWavesTotal) {
        // Wave-uniform: force scalar path so the row-data VMEM queue stays clean.
        const int   t     = __builtin_amdgcn_readfirstlane(tokens[tok]);
        const float scale = absmax[t];

        const int4* __restrict__ wrow = (const int4*)(weight + (size_t)t * DIM);
        fx4* __restrict__ orow        = (fx4*)(out + (size_t)tok * DIM);

        // 4096 elems / 4-per-vec = 1024 int4; 64 lanes -> 16 int4 per lane.
        // Issue all 16 loads first: 16 KiB in flight per wave.
        int4 q[16];
#pragma unroll
        for (int i = 0; i < 16; ++i)
            q[i] = wrow[lane + i * 64];

#pragma unroll
        for (int i = 0; i < 16; ++i) {
            fx4 o;
            o.x = lut[q[i].x & 255] * scale;
            o.y = lut[q[i].y & 255] * scale;
            o.z = lut[q[i].z & 255] * scale;
            o.w = lut[q[i].w & 255] * scale;
            __builtin_nontemporal_store(o, &orow[lane + i * 64]);
        }
    }
}

extern "C" void kernel_launch(void* const* d_in, const int* in_sizes, int n_in,
                              void* d_out, int out_size, void* d_ws, size_t ws_size,
                              hipStream_t stream)
{
    const int*   tokens = (const int*)d_in[0];    // [4, 2048] int32
    const int*   weight = (const int*)d_in[1];    // [50400, 4096] int32
    const float* absmax = (const float*)d_in[2];  // [50400] fp32
    const float* code   = (const float*)d_in[3];  // [256] fp32
    float*       out    = (float*)d_out;          // [4, 2048, 4096] fp32

    const int n_tokens = in_sizes[0];             // 8192

    int blocks = (n_tokens + 3) / 4;              // one token per wave
    if (blocks > 2048) blocks = 2048;             // 2048*4 = 8192 waves; grid-stride covers rest
    if (blocks < 1)    blocks = 1;

    bnb_embed_kernel<<<blocks, 256, 0, stream>>>(tokens, weight, absmax, code, out, n_tokens);
}